// Round 1
// 336.662 us; speedup vs baseline: 1.1643x; 1.1643x over previous
//
#include <hip/hip_runtime.h>
#include <hip/hip_bf16.h>
#include <cstddef>
#include <cstdint>

// Problem constants
#define BB 4
#define CC 512
#define TT 2048
#define NN 4096
#define HH 4
// d = CC/HH = 128

constexpr float KFAC       = 0.04419417382415922f;           // 1/(sqrt(128)*2)
constexpr float INV_S18    = 1.0f / 262144.0f;               // 2^-18 (undo two x512)
constexpr float INV_SCALE2 = 1.0f / (512.0f * 512.0f);

typedef _Float16 f16x8 __attribute__((ext_vector_type(8)));
typedef _Float16 f16x4 __attribute__((ext_vector_type(4)));
typedef float    f32x4 __attribute__((ext_vector_type(4)));

__device__ __forceinline__ void gld16(const void* g, void* s) {
    __builtin_amdgcn_global_load_lds(
        (const __attribute__((address_space(1))) void*)g,
        (__attribute__((address_space(3))) void*)s, 16, 0, 0);
}

struct HL { _Float16 h, l; };
__device__ __forceinline__ HL split512(float x) {
    float v = x * 512.0f;
    _Float16 h = (_Float16)v;
    return { h, (_Float16)(v - (float)h) };
}

// ---------------------------------------------------------------------------
// Prep 1: elementwise split (x512) of cb [N][C] -> cbhi/cblo fp16 [N][C]
// ---------------------------------------------------------------------------
__global__ __launch_bounds__(256) void k_split(
    const float* __restrict__ src, _Float16* __restrict__ hi, _Float16* __restrict__ lo, int n4)
{
    int q = blockIdx.x * 256 + threadIdx.x;
    if (q >= n4) return;
    float4 v = *(const float4*)(src + (size_t)q * 4);
    f16x4 H, L;
    HL a = split512(v.x); H[0] = a.h; L[0] = a.l;
    HL b = split512(v.y); H[1] = b.h; L[1] = b.l;
    HL c = split512(v.z); H[2] = c.h; L[2] = c.l;
    HL d = split512(v.w); H[3] = d.h; L[3] = d.l;
    *(f16x4*)(hi + (size_t)q * 4) = H;
    *(f16x4*)(lo + (size_t)q * 4) = L;
}

// ---------------------------------------------------------------------------
// Prep 2: transpose + split (x512): src fp32 [R][S] -> dst hi/lo fp16 [S][R]
// 64x64 tiles. Used for hs (per batch: [C][T] -> [T][C]) and weights.
// ---------------------------------------------------------------------------
__device__ __forceinline__ void tsplit_body(
    const float* __restrict__ src, _Float16* __restrict__ hi, _Float16* __restrict__ lo,
    int S, int R, int r0, int s0)
{
    __shared__ float ls[64][65];
    const int tid = threadIdx.x;
    #pragma unroll
    for (int i = 0; i < 4; ++i) {
        int q = tid + i * 256;
        int row = q >> 4, c4 = (q & 15) * 4;
        float4 v = *(const float4*)(src + (size_t)(r0 + row) * S + s0 + c4);
        ls[row][c4] = v.x; ls[row][c4 + 1] = v.y;
        ls[row][c4 + 2] = v.z; ls[row][c4 + 3] = v.w;
    }
    __syncthreads();
    #pragma unroll
    for (int i = 0; i < 2; ++i) {
        int q = tid + i * 256;
        int orow = q >> 3, seg = (q & 7) * 8;
        f16x8 H, L;
        #pragma unroll
        for (int j = 0; j < 8; ++j) {
            HL s = split512(ls[seg + j][orow]);
            H[j] = s.h; L[j] = s.l;
        }
        size_t off = (size_t)(s0 + orow) * R + r0 + seg;
        *(f16x8*)(hi + off) = H;
        *(f16x8*)(lo + off) = L;
    }
}

__global__ __launch_bounds__(256) void k_tsplit(
    const float* __restrict__ src, _Float16* __restrict__ hi, _Float16* __restrict__ lo,
    long sbatch, long dbatch, int S, int R)
{
    src += (size_t)blockIdx.z * sbatch;
    hi  += (size_t)blockIdx.z * dbatch;
    lo  += (size_t)blockIdx.z * dbatch;
    tsplit_body(src, hi, lo, S, R, blockIdx.y * 64, blockIdx.x * 64);
}

// Weights: Wq/Wk/Wv [C][C] -> W^T hi/lo [C][C], selected by blockIdx.z
__global__ __launch_bounds__(256) void k_tsplit_w(
    const float* __restrict__ w0, const float* __restrict__ w1, const float* __restrict__ w2,
    _Float16* __restrict__ h0, _Float16* __restrict__ h1, _Float16* __restrict__ h2,
    _Float16* __restrict__ l0, _Float16* __restrict__ l1, _Float16* __restrict__ l2)
{
    const int z = blockIdx.z;
    const float* src = z == 0 ? w0 : z == 1 ? w1 : w2;
    _Float16* hi = z == 0 ? h0 : z == 1 ? h1 : h2;
    _Float16* lo = z == 0 ? l0 : z == 1 ? l1 : l2;
    tsplit_body(src, hi, lo, CC, CC, blockIdx.y * 64, blockIdx.x * 64);
}

// ---------------------------------------------------------------------------
// MFMA tile core: 128x128 output tile, BK=32, 4 waves (2x2), 4x4 16x16x32
// MFMAs per wave, 3-term split-fp16. A rows = output rows, B rows = output
// cols, both LDS-staged [row][k] via global_load_lds width 16.
// ---------------------------------------------------------------------------
#define MFMA_TILE_DECLS                                                       \
    __shared__ __align__(16) _Float16 Ah[128][32];                            \
    __shared__ __align__(16) _Float16 Al[128][32];                            \
    __shared__ __align__(16) _Float16 Bh[128][32];                            \
    __shared__ __align__(16) _Float16 Bl[128][32];                            \
    const int tid  = threadIdx.x;                                             \
    const int w    = tid >> 6;                                                \
    const int l    = tid & 63;                                                \
    const int quad = l >> 4;                                                  \
    const int l15  = l & 15;                                                  \
    const int wm   = (w >> 1) * 64;                                           \
    const int wn   = (w & 1) * 64;                                            \
    const int rA   = l >> 2;                                                  \
    const int cA   = (l & 3) * 8;                                             \
    f32x4 acc[4][4];                                                          \
    _Pragma("unroll") for (int i = 0; i < 4; ++i)                             \
        _Pragma("unroll") for (int j = 0; j < 4; ++j)                         \
            acc[i][j] = (f32x4){0.f, 0.f, 0.f, 0.f};

#define MFMA_TILE_STAGE(pAh, pAl, pBh, pBl, k0, srcStride)                    \
    gld16(pAh + k0,                    &Ah[w * 32][0]);                       \
    gld16(pAh + k0 + 16 * (srcStride), &Ah[w * 32 + 16][0]);                  \
    gld16(pAl + k0,                    &Al[w * 32][0]);                       \
    gld16(pAl + k0 + 16 * (srcStride), &Al[w * 32 + 16][0]);                  \
    gld16(pBh + k0,                    &Bh[w * 32][0]);                       \
    gld16(pBh + k0 + 16 * (srcStride), &Bh[w * 32 + 16][0]);                  \
    gld16(pBl + k0,                    &Bl[w * 32][0]);                       \
    gld16(pBl + k0 + 16 * (srcStride), &Bl[w * 32 + 16][0]);

#define MFMA_TILE_COMPUTE                                                     \
    {                                                                         \
        f16x8 fah[4], fal[4], fbh[4], fbl[4];                                 \
        _Pragma("unroll") for (int i = 0; i < 4; ++i) {                       \
            fah[i] = *(const f16x8*)&Ah[wm + i * 16 + l15][quad * 8];         \
            fal[i] = *(const f16x8*)&Al[wm + i * 16 + l15][quad * 8];         \
            fbh[i] = *(const f16x8*)&Bh[wn + i * 16 + l15][quad * 8];         \
            fbl[i] = *(const f16x8*)&Bl[wn + i * 16 + l15][quad * 8];         \
        }                                                                     \
        _Pragma("unroll") for (int i = 0; i < 4; ++i)                         \
            _Pragma("unroll") for (int j = 0; j < 4; ++j) {                   \
                acc[i][j] = __builtin_amdgcn_mfma_f32_16x16x32_f16(fah[i], fbh[j], acc[i][j], 0, 0, 0); \
                acc[i][j] = __builtin_amdgcn_mfma_f32_16x16x32_f16(fah[i], fbl[j], acc[i][j], 0, 0, 0); \
                acc[i][j] = __builtin_amdgcn_mfma_f32_16x16x32_f16(fal[i], fbh[j], acc[i][j], 0, 0, 0); \
            }                                                                 \
    }

// ---------------------------------------------------------------------------
// Merged projections (one dispatch -> 512 blocks, 2 blocks/CU).
// z=0          : q-proj + gate  (rows = b*T+t over B*T)
// z=1, y <  32 : khi/klo = split((cb@Wk + bk)*512)
// z=1, y >= 32 : vproj = cb@Wv + bv (fp32)
// ---------------------------------------------------------------------------
__global__ __launch_bounds__(256, 2) void k_proj_all(
    const _Float16* __restrict__ hsTh, const _Float16* __restrict__ hsTl,
    const _Float16* __restrict__ cbhi, const _Float16* __restrict__ cblo,
    const _Float16* __restrict__ wqTh, const _Float16* __restrict__ wqTl,
    const _Float16* __restrict__ wkTh, const _Float16* __restrict__ wkTl,
    const _Float16* __restrict__ wvTh, const _Float16* __restrict__ wvTl,
    const float* __restrict__ bq, const float* __restrict__ bk, const float* __restrict__ bv,
    const float* __restrict__ Wp, const float* __restrict__ bp,
    _Float16* __restrict__ qhi, _Float16* __restrict__ qlo,
    _Float16* __restrict__ khi, _Float16* __restrict__ klo, float* __restrict__ vproj)
{
    const int z    = blockIdx.z;
    const int y    = blockIdx.y;
    const int c0   = blockIdx.x * 128;                 // cout
    const int path = z == 0 ? 0 : (y < 32 ? 1 : 2);    // 0=q 1=k 2=v
    const int m0   = (z == 0 ? y : (y & 31)) * 128;    // row block
    const int hblk = c0 >> 7;                          // head (d=128), q-path only

    const _Float16* srcAh = z == 0 ? hsTh : cbhi;
    const _Float16* srcAl = z == 0 ? hsTl : cblo;
    const _Float16* bTh   = path == 0 ? wqTh : path == 1 ? wkTh : wvTh;
    const _Float16* bTl   = path == 0 ? wqTl : path == 1 ? wkTl : wvTl;
    const float*    bias  = path == 0 ? bq   : path == 1 ? bk   : bv;

    MFMA_TILE_DECLS
    __shared__ float wp_sh[32];
    __shared__ float gate_sh[128];
    float gate = 0.f;

    const _Float16* pAh = srcAh + (size_t)(m0 + w * 32 + rA) * CC + cA;
    const _Float16* pAl = srcAl + (size_t)(m0 + w * 32 + rA) * CC + cA;
    const _Float16* pBh = bTh   + (size_t)(c0 + w * 32 + rA) * CC + cA;
    const _Float16* pBl = bTl   + (size_t)(c0 + w * 32 + rA) * CC + cA;

    for (int k0 = 0; k0 < CC; k0 += 32) {
        MFMA_TILE_STAGE(pAh, pAl, pBh, pBl, k0, CC)
        if (path == 0 && tid < 32) wp_sh[tid] = Wp[(size_t)(k0 + tid) * HH + hblk];
        __syncthreads();
        MFMA_TILE_COMPUTE
        if (path == 0 && tid < 128) {
            #pragma unroll
            for (int s = 0; s < 4; ++s) {
                f16x8 hv = *(const f16x8*)&Ah[tid][s * 8];
                f16x8 lv = *(const f16x8*)&Al[tid][s * 8];
                #pragma unroll
                for (int jj = 0; jj < 8; ++jj)
                    gate = fmaf((float)hv[jj] + (float)lv[jj], wp_sh[s * 8 + jj], gate);
            }
        }
        __syncthreads();
    }

    if (path == 0) {
        if (tid < 128)
            gate_sh[tid] = (gate * (1.0f / 512.0f) + bp[hblk]) * KFAC;  // split512 adds the x512
        __syncthreads();
        #pragma unroll
        for (int i = 0; i < 4; ++i)
            #pragma unroll
            for (int j = 0; j < 4; ++j) {
                int col = c0 + wn + j * 16 + l15;
                float bi = bias[col];
                #pragma unroll
                for (int r = 0; r < 4; ++r) {
                    int rloc = wm + i * 16 + quad * 4 + r;
                    float v = fmaf(acc[i][j][r], INV_S18, bi) * gate_sh[rloc];
                    HL s = split512(v);
                    qhi[(size_t)(m0 + rloc) * CC + col] = s.h;
                    qlo[(size_t)(m0 + rloc) * CC + col] = s.l;
                }
            }
    } else if (path == 1) {
        #pragma unroll
        for (int i = 0; i < 4; ++i)
            #pragma unroll
            for (int j = 0; j < 4; ++j) {
                int col = c0 + wn + j * 16 + l15;
                float bi = bias[col];
                #pragma unroll
                for (int r = 0; r < 4; ++r) {
                    int row = m0 + wm + i * 16 + quad * 4 + r;
                    float v = fmaf(acc[i][j][r], INV_S18, bi);
                    HL s = split512(v);
                    khi[(size_t)row * CC + col] = s.h;
                    klo[(size_t)row * CC + col] = s.l;
                }
            }
    } else {
        #pragma unroll
        for (int i = 0; i < 4; ++i)
            #pragma unroll
            for (int j = 0; j < 4; ++j) {
                int col = c0 + wn + j * 16 + l15;
                float bi = bias[col];
                #pragma unroll
                for (int r = 0; r < 4; ++r) {
                    int row = m0 + wm + i * 16 + quad * 4 + r;
                    vproj[(size_t)row * CC + col] = fmaf(acc[i][j][r], INV_S18, bi);
                }
            }
    }
}

// ---------------------------------------------------------------------------
// logits[b][n][t] = 2^-18 * sum_c (khi+klo)[n][c] * (qhi+qlo)[b*T+t][c]
// Epilogue additionally produces per-block partial argmax over the tile's
// 128 n-rows for each t-column (first-max tie-break preserved):
//   pval/pidx [B][32][T]
// ---------------------------------------------------------------------------
__global__ __launch_bounds__(256, 2) void k_logits_mfma(
    const _Float16* __restrict__ khi, const _Float16* __restrict__ klo,
    const _Float16* __restrict__ qhi, const _Float16* __restrict__ qlo,
    float* __restrict__ logits,       // [B][N][T]
    float* __restrict__ pval,         // [B][32][T]
    int*   __restrict__ pidx)         // [B][32][T]
{
    const int b  = blockIdx.z;
    const int t0 = blockIdx.x * 128;
    const int n0 = blockIdx.y * 128;

    MFMA_TILE_DECLS
    __shared__ float rval[128];
    __shared__ int   ridx[128];

    const _Float16* pAh = khi + (size_t)(n0 + w * 32 + rA) * CC + cA;
    const _Float16* pAl = klo + (size_t)(n0 + w * 32 + rA) * CC + cA;
    const _Float16* pBh = qhi + ((size_t)b * TT + t0 + w * 32 + rA) * CC + cA;
    const _Float16* pBl = qlo + ((size_t)b * TT + t0 + w * 32 + rA) * CC + cA;

    for (int k0 = 0; k0 < CC; k0 += 32) {
        MFMA_TILE_STAGE(pAh, pAl, pBh, pBl, k0, CC)
        __syncthreads();
        MFMA_TILE_COMPUTE
        __syncthreads();
    }

    // Store logits + per-thread/quad partial argmax (rows ascending, strict >
    // keeps the first max, matching jnp.argmax).
    float bvj[4]; int bnj[4];
    #pragma unroll
    for (int j = 0; j < 4; ++j) {
        int col = t0 + wn + j * 16 + l15;
        float bv = -3.0e38f; int bn = 0;
        #pragma unroll
        for (int i = 0; i < 4; ++i) {
            #pragma unroll
            for (int r = 0; r < 4; ++r) {
                int row = n0 + wm + i * 16 + quad * 4 + r;
                float v = acc[i][j][r] * INV_SCALE2;
                logits[((size_t)b * NN + row) * TT + col] = v;
                if (v > bv) { bv = v; bn = row; }
            }
        }
        // combine across the 4 quads holding the same column (rows interleave
        // across quads -> need explicit min-index tie-break)
        #pragma unroll
        for (int m = 16; m <= 32; m <<= 1) {
            float ov = __shfl_xor(bv, m, 64);
            int   on = __shfl_xor(bn, m, 64);
            if (ov > bv || (ov == bv && on < bn)) { bv = ov; bn = on; }
        }
        bvj[j] = bv; bnj[j] = bn;
    }
    // combine wave pairs (w, w+2) sharing the same 64 columns. wm=64 rows are
    // all larger than wm=0 rows, so on ties the wm=0 wave must win: only take
    // the other side's value when strictly greater.
    if (w >= 2 && l < 16) {
        #pragma unroll
        for (int j = 0; j < 4; ++j) {
            rval[wn + j * 16 + l] = bvj[j];
            ridx[wn + j * 16 + l] = bnj[j];
        }
    }
    __syncthreads();
    if (w < 2 && l < 16) {
        #pragma unroll
        for (int j = 0; j < 4; ++j) {
            int cl = wn + j * 16 + l;
            float bv = bvj[j]; int bn = bnj[j];
            float ov = rval[cl];
            if (ov > bv) { bv = ov; bn = ridx[cl]; }
            size_t o = ((size_t)b * 32 + (n0 >> 7)) * TT + t0 + cl;
            pval[o] = bv;
            pidx[o] = bn;
        }
    }
}

// ---------------------------------------------------------------------------
// Finalize: reduce 32 partial argmaxes per (b,t) (k ascending + strict > ==
// global first-max), then gather z_q rows from vproj.
// ---------------------------------------------------------------------------
__global__ __launch_bounds__(256) void k_finalize(
    const float* __restrict__ pval,    // [B][32][T]
    const int*   __restrict__ pidx,    // [B][32][T]
    const float* __restrict__ vproj,   // [N][C]
    float* __restrict__ idx_out,       // [B][T] (float)
    float* __restrict__ zq)            // [B][C][T]
{
    const int b  = blockIdx.y;
    const int t0 = blockIdx.x * 32;
    const int tid = threadIdx.x;

    __shared__ int sfin[32];
    if (tid < 32) {
        const int t = t0 + tid;
        float bv = -3.0e38f; int bn = 0;
        #pragma unroll
        for (int k = 0; k < 32; ++k) {
            size_t o = ((size_t)b * 32 + k) * TT + t;
            float v = pval[o];
            if (v > bv) { bv = v; bn = pidx[o]; }
        }
        idx_out[(size_t)b * TT + t] = (float)bn;
        sfin[tid] = bn;
    }
    __syncthreads();
    for (int pos = tid; pos < 32 * CC; pos += 256) {
        int c = pos >> 5, tl = pos & 31;
        zq[((size_t)b * CC + c) * TT + t0 + tl] = vproj[(size_t)sfin[tl] * CC + c];
    }
}

// ---------------------------------------------------------------------------
extern "C" void kernel_launch(void* const* d_in, const int* in_sizes, int n_in,
                              void* d_out, int out_size, void* d_ws, size_t ws_size,
                              hipStream_t stream)
{
    (void)in_sizes; (void)n_in; (void)out_size; (void)ws_size;
    const float* hs = (const float*)d_in[0];
    const float* cb = (const float*)d_in[1];
    const float* Wq = (const float*)d_in[2];
    const float* bq = (const float*)d_in[3];
    const float* Wk = (const float*)d_in[4];
    const float* bk = (const float*)d_in[5];
    const float* Wv = (const float*)d_in[6];
    const float* bv = (const float*)d_in[7];
    const float* Wp = (const float*)d_in[8];
    const float* bp = (const float*)d_in[9];

    char* ws = (char*)d_ws;
    const size_t MB = 1024 * 1024;
    _Float16* hsTh = (_Float16*)(ws);              // [B*T][C] 8 MB
    _Float16* hsTl = (_Float16*)(ws + 8  * MB);
    _Float16* qhi  = (_Float16*)(ws + 16 * MB);    // [B*T][C] 8 MB
    _Float16* qlo  = (_Float16*)(ws + 24 * MB);
    _Float16* cbhi = (_Float16*)(ws + 32 * MB);    // [N][C]   4 MB
    _Float16* cblo = (_Float16*)(ws + 36 * MB);
    _Float16* khi  = (_Float16*)(ws + 40 * MB);    // [N][C]   4 MB
    _Float16* klo  = (_Float16*)(ws + 44 * MB);
    float*    vproj= (float*)   (ws + 48 * MB);    // [N][C]   8 MB fp32
    _Float16* wqTh = (_Float16*)(ws + 56 * MB);    // [C][C]   0.5 MB each
    _Float16* wqTl = (_Float16*)(ws + 56 * MB + 524288);
    _Float16* wkTh = (_Float16*)(ws + 57 * MB);
    _Float16* wkTl = (_Float16*)(ws + 57 * MB + 524288);
    _Float16* wvTh = (_Float16*)(ws + 58 * MB);
    _Float16* wvTl = (_Float16*)(ws + 58 * MB + 524288);
    // Partial argmax buffers: alias the cbhi/cblo region. cbhi/cblo are only
    // read by k_proj_all, which completes (stream order) before k_logits_mfma
    // writes pval/pidx. 1 MB each.
    float* pval = (float*)(ws + 32 * MB);
    int*   pidx = (int*)  (ws + 33 * MB);

    float* logits = (float*)d_out;                  // B*N*T
    float* idxf   = logits + (size_t)BB * NN * TT;  // B*T
    float* zq     = idxf + (size_t)BB * TT;         // B*C*T

    // Prep
    k_split<<<dim3((NN * CC / 4 + 255) / 256), 256, 0, stream>>>(
        cb, cbhi, cblo, NN * CC / 4);
    k_tsplit<<<dim3(TT / 64, CC / 64, BB), 256, 0, stream>>>(
        hs, hsTh, hsTl, (long)CC * TT, (long)TT * CC, TT, CC);
    k_tsplit_w<<<dim3(CC / 64, CC / 64, 3), 256, 0, stream>>>(
        Wq, Wk, Wv, wqTh, wkTh, wvTh, wqTl, wkTl, wvTl);

    // All projections in one dispatch (512 blocks -> 2 blocks/CU)
    k_proj_all<<<dim3(CC / 128, 64, 2), 256, 0, stream>>>(
        hsTh, hsTl, cbhi, cblo,
        wqTh, wqTl, wkTh, wkTl, wvTh, wvTl,
        bq, bk, bv, Wp, bp,
        qhi, qlo, khi, klo, vproj);

    // Logits (MFMA) + fused partial argmax
    k_logits_mfma<<<dim3(TT / 128, NN / 128, BB), 256, 0, stream>>>(
        khi, klo, qhi, qlo, logits, pval, pidx);

    // Final argmax reduce + gather
    k_finalize<<<dim3(TT / 32, BB), 256, 0, stream>>>(
        pval, pidx, vproj, idxf, zq);
}

// Round 2
// 331.473 us; speedup vs baseline: 1.1825x; 1.0157x over previous
//
#include <hip/hip_runtime.h>
#include <hip/hip_bf16.h>
#include <cstddef>
#include <cstdint>

// Problem constants
#define BB 4
#define CC 512
#define TT 2048
#define NN 4096
#define HH 4
// d = CC/HH = 128

constexpr float KFAC       = 0.04419417382415922f;           // 1/(sqrt(128)*2)
constexpr float INV_S18    = 1.0f / 262144.0f;               // 2^-18 (undo two x512)
constexpr float INV_SCALE2 = 1.0f / (512.0f * 512.0f);

typedef _Float16 f16x8 __attribute__((ext_vector_type(8)));
typedef _Float16 f16x4 __attribute__((ext_vector_type(4)));
typedef float    f32x4 __attribute__((ext_vector_type(4)));

__device__ __forceinline__ void gld16(const void* g, void* s) {
    __builtin_amdgcn_global_load_lds(
        (const __attribute__((address_space(1))) void*)g,
        (__attribute__((address_space(3))) void*)s, 16, 0, 0);
}

struct HL { _Float16 h, l; };
__device__ __forceinline__ HL split512(float x) {
    float v = x * 512.0f;
    _Float16 h = (_Float16)v;
    return { h, (_Float16)(v - (float)h) };
}

// ---------------------------------------------------------------------------
// Prep 1: elementwise split (x512) of cb [N][C] -> cbhi/cblo fp16 [N][C]
// ---------------------------------------------------------------------------
__global__ __launch_bounds__(256) void k_split(
    const float* __restrict__ src, _Float16* __restrict__ hi, _Float16* __restrict__ lo, int n4)
{
    int q = blockIdx.x * 256 + threadIdx.x;
    if (q >= n4) return;
    float4 v = *(const float4*)(src + (size_t)q * 4);
    f16x4 H, L;
    HL a = split512(v.x); H[0] = a.h; L[0] = a.l;
    HL b = split512(v.y); H[1] = b.h; L[1] = b.l;
    HL c = split512(v.z); H[2] = c.h; L[2] = c.l;
    HL d = split512(v.w); H[3] = d.h; L[3] = d.l;
    *(f16x4*)(hi + (size_t)q * 4) = H;
    *(f16x4*)(lo + (size_t)q * 4) = L;
}

// ---------------------------------------------------------------------------
// Prep 2: transpose + split (x512): src fp32 [R][S] -> dst hi/lo fp16 [S][R]
// ---------------------------------------------------------------------------
__device__ __forceinline__ void tsplit_body(
    const float* __restrict__ src, _Float16* __restrict__ hi, _Float16* __restrict__ lo,
    int S, int R, int r0, int s0)
{
    __shared__ float ls[64][65];
    const int tid = threadIdx.x;
    #pragma unroll
    for (int i = 0; i < 4; ++i) {
        int q = tid + i * 256;
        int row = q >> 4, c4 = (q & 15) * 4;
        float4 v = *(const float4*)(src + (size_t)(r0 + row) * S + s0 + c4);
        ls[row][c4] = v.x; ls[row][c4 + 1] = v.y;
        ls[row][c4 + 2] = v.z; ls[row][c4 + 3] = v.w;
    }
    __syncthreads();
    #pragma unroll
    for (int i = 0; i < 2; ++i) {
        int q = tid + i * 256;
        int orow = q >> 3, seg = (q & 7) * 8;
        f16x8 H, L;
        #pragma unroll
        for (int j = 0; j < 8; ++j) {
            HL s = split512(ls[seg + j][orow]);
            H[j] = s.h; L[j] = s.l;
        }
        size_t off = (size_t)(s0 + orow) * R + r0 + seg;
        *(f16x8*)(hi + off) = H;
        *(f16x8*)(lo + off) = L;
    }
}

__global__ __launch_bounds__(256) void k_tsplit(
    const float* __restrict__ src, _Float16* __restrict__ hi, _Float16* __restrict__ lo,
    long sbatch, long dbatch, int S, int R)
{
    src += (size_t)blockIdx.z * sbatch;
    hi  += (size_t)blockIdx.z * dbatch;
    lo  += (size_t)blockIdx.z * dbatch;
    tsplit_body(src, hi, lo, S, R, blockIdx.y * 64, blockIdx.x * 64);
}

__global__ __launch_bounds__(256) void k_tsplit_w(
    const float* __restrict__ w0, const float* __restrict__ w1, const float* __restrict__ w2,
    _Float16* __restrict__ h0, _Float16* __restrict__ h1, _Float16* __restrict__ h2,
    _Float16* __restrict__ l0, _Float16* __restrict__ l1, _Float16* __restrict__ l2)
{
    const int z = blockIdx.z;
    const float* src = z == 0 ? w0 : z == 1 ? w1 : w2;
    _Float16* hi = z == 0 ? h0 : z == 1 ? h1 : h2;
    _Float16* lo = z == 0 ? l0 : z == 1 ? l1 : l2;
    tsplit_body(src, hi, lo, CC, CC, blockIdx.y * 64, blockIdx.x * 64);
}

// ---------------------------------------------------------------------------
// MFMA tile core (projections): 128x128 tile, BK=32, 4 waves, 3-term split.
// ---------------------------------------------------------------------------
#define MFMA_TILE_DECLS                                                       \
    __shared__ __align__(16) _Float16 Ah[128][32];                            \
    __shared__ __align__(16) _Float16 Al[128][32];                            \
    __shared__ __align__(16) _Float16 Bh[128][32];                            \
    __shared__ __align__(16) _Float16 Bl[128][32];                            \
    const int tid  = threadIdx.x;                                             \
    const int w    = tid >> 6;                                                \
    const int l    = tid & 63;                                                \
    const int quad = l >> 4;                                                  \
    const int l15  = l & 15;                                                  \
    const int wm   = (w >> 1) * 64;                                           \
    const int wn   = (w & 1) * 64;                                            \
    const int rA   = l >> 2;                                                  \
    const int cA   = (l & 3) * 8;                                             \
    f32x4 acc[4][4];                                                          \
    _Pragma("unroll") for (int i = 0; i < 4; ++i)                             \
        _Pragma("unroll") for (int j = 0; j < 4; ++j)                         \
            acc[i][j] = (f32x4){0.f, 0.f, 0.f, 0.f};

#define MFMA_TILE_STAGE(pAh, pAl, pBh, pBl, k0, srcStride)                    \
    gld16(pAh + k0,                    &Ah[w * 32][0]);                       \
    gld16(pAh + k0 + 16 * (srcStride), &Ah[w * 32 + 16][0]);                  \
    gld16(pAl + k0,                    &Al[w * 32][0]);                       \
    gld16(pAl + k0 + 16 * (srcStride), &Al[w * 32 + 16][0]);                  \
    gld16(pBh + k0,                    &Bh[w * 32][0]);                       \
    gld16(pBh + k0 + 16 * (srcStride), &Bh[w * 32 + 16][0]);                  \
    gld16(pBl + k0,                    &Bl[w * 32][0]);                       \
    gld16(pBl + k0 + 16 * (srcStride), &Bl[w * 32 + 16][0]);

#define MFMA_TILE_COMPUTE                                                     \
    {                                                                         \
        f16x8 fah[4], fal[4], fbh[4], fbl[4];                                 \
        _Pragma("unroll") for (int i = 0; i < 4; ++i) {                       \
            fah[i] = *(const f16x8*)&Ah[wm + i * 16 + l15][quad * 8];         \
            fal[i] = *(const f16x8*)&Al[wm + i * 16 + l15][quad * 8];         \
            fbh[i] = *(const f16x8*)&Bh[wn + i * 16 + l15][quad * 8];         \
            fbl[i] = *(const f16x8*)&Bl[wn + i * 16 + l15][quad * 8];         \
        }                                                                     \
        _Pragma("unroll") for (int i = 0; i < 4; ++i)                         \
            _Pragma("unroll") for (int j = 0; j < 4; ++j) {                   \
                acc[i][j] = __builtin_amdgcn_mfma_f32_16x16x32_f16(fah[i], fbh[j], acc[i][j], 0, 0, 0); \
                acc[i][j] = __builtin_amdgcn_mfma_f32_16x16x32_f16(fah[i], fbl[j], acc[i][j], 0, 0, 0); \
                acc[i][j] = __builtin_amdgcn_mfma_f32_16x16x32_f16(fal[i], fbh[j], acc[i][j], 0, 0, 0); \
            }                                                                 \
    }

// ---------------------------------------------------------------------------
// Merged projections (512 blocks, 2 blocks/CU).
// z=0: q-proj + gate; z=1,y<32: k-proj split; z=1,y>=32: v-proj fp32.
// ---------------------------------------------------------------------------
__global__ __launch_bounds__(256, 2) void k_proj_all(
    const _Float16* __restrict__ hsTh, const _Float16* __restrict__ hsTl,
    const _Float16* __restrict__ cbhi, const _Float16* __restrict__ cblo,
    const _Float16* __restrict__ wqTh, const _Float16* __restrict__ wqTl,
    const _Float16* __restrict__ wkTh, const _Float16* __restrict__ wkTl,
    const _Float16* __restrict__ wvTh, const _Float16* __restrict__ wvTl,
    const float* __restrict__ bq, const float* __restrict__ bk, const float* __restrict__ bv,
    const float* __restrict__ Wp, const float* __restrict__ bp,
    _Float16* __restrict__ qhi, _Float16* __restrict__ qlo,
    _Float16* __restrict__ khi, _Float16* __restrict__ klo, float* __restrict__ vproj)
{
    const int z    = blockIdx.z;
    const int y    = blockIdx.y;
    const int c0   = blockIdx.x * 128;
    const int path = z == 0 ? 0 : (y < 32 ? 1 : 2);
    const int m0   = (z == 0 ? y : (y & 31)) * 128;
    const int hblk = c0 >> 7;

    const _Float16* srcAh = z == 0 ? hsTh : cbhi;
    const _Float16* srcAl = z == 0 ? hsTl : cblo;
    const _Float16* bTh   = path == 0 ? wqTh : path == 1 ? wkTh : wvTh;
    const _Float16* bTl   = path == 0 ? wqTl : path == 1 ? wkTl : wvTl;
    const float*    bias  = path == 0 ? bq   : path == 1 ? bk   : bv;

    MFMA_TILE_DECLS
    __shared__ float wp_sh[32];
    __shared__ float gate_sh[128];
    float gate = 0.f;

    const _Float16* pAh = srcAh + (size_t)(m0 + w * 32 + rA) * CC + cA;
    const _Float16* pAl = srcAl + (size_t)(m0 + w * 32 + rA) * CC + cA;
    const _Float16* pBh = bTh   + (size_t)(c0 + w * 32 + rA) * CC + cA;
    const _Float16* pBl = bTl   + (size_t)(c0 + w * 32 + rA) * CC + cA;

    for (int k0 = 0; k0 < CC; k0 += 32) {
        MFMA_TILE_STAGE(pAh, pAl, pBh, pBl, k0, CC)
        if (path == 0 && tid < 32) wp_sh[tid] = Wp[(size_t)(k0 + tid) * HH + hblk];
        __syncthreads();
        MFMA_TILE_COMPUTE
        if (path == 0 && tid < 128) {
            #pragma unroll
            for (int s = 0; s < 4; ++s) {
                f16x8 hv = *(const f16x8*)&Ah[tid][s * 8];
                f16x8 lv = *(const f16x8*)&Al[tid][s * 8];
                #pragma unroll
                for (int jj = 0; jj < 8; ++jj)
                    gate = fmaf((float)hv[jj] + (float)lv[jj], wp_sh[s * 8 + jj], gate);
            }
        }
        __syncthreads();
    }

    if (path == 0) {
        if (tid < 128)
            gate_sh[tid] = (gate * (1.0f / 512.0f) + bp[hblk]) * KFAC;
        __syncthreads();
        #pragma unroll
        for (int i = 0; i < 4; ++i)
            #pragma unroll
            for (int j = 0; j < 4; ++j) {
                int col = c0 + wn + j * 16 + l15;
                float bi = bias[col];
                #pragma unroll
                for (int r = 0; r < 4; ++r) {
                    int rloc = wm + i * 16 + quad * 4 + r;
                    float v = fmaf(acc[i][j][r], INV_S18, bi) * gate_sh[rloc];
                    HL s = split512(v);
                    qhi[(size_t)(m0 + rloc) * CC + col] = s.h;
                    qlo[(size_t)(m0 + rloc) * CC + col] = s.l;
                }
            }
    } else if (path == 1) {
        #pragma unroll
        for (int i = 0; i < 4; ++i)
            #pragma unroll
            for (int j = 0; j < 4; ++j) {
                int col = c0 + wn + j * 16 + l15;
                float bi = bias[col];
                #pragma unroll
                for (int r = 0; r < 4; ++r) {
                    int row = m0 + wm + i * 16 + quad * 4 + r;
                    float v = fmaf(acc[i][j][r], INV_S18, bi);
                    HL s = split512(v);
                    khi[(size_t)row * CC + col] = s.h;
                    klo[(size_t)row * CC + col] = s.l;
                }
            }
    } else {
        #pragma unroll
        for (int i = 0; i < 4; ++i)
            #pragma unroll
            for (int j = 0; j < 4; ++j) {
                int col = c0 + wn + j * 16 + l15;
                float bi = bias[col];
                #pragma unroll
                for (int r = 0; r < 4; ++r) {
                    int row = m0 + wm + i * 16 + quad * 4 + r;
                    vproj[(size_t)row * CC + col] = fmaf(acc[i][j][r], INV_S18, bi);
                }
            }
    }
}

// ---------------------------------------------------------------------------
// Logits as a 256x256-tile phase-split GEMM over virtual K'=1536:
//   segments: (khi,qhi) + (klo,qhi) + (khi,qlo)  == 3-term split product.
// 8 waves (2M x 4N), BK=64, double-buffered 128KB LDS, st_16x32 XOR swizzle
// (linear LDS dest for global_load_lds + pre-swizzled global source +
// swizzled ds_read). 4 phases per K-tile (one C-quadrant each, 16 MFMA).
// Staging for K-tile t+1 issued at phases 0-1 of tile t; vmcnt(0) at phase 3.
// Fused partial argmax over the 256 n-rows -> pval/pidx [B][16][T].
// ---------------------------------------------------------------------------
#define BAR   __builtin_amdgcn_s_barrier()
#define LGKM0 { asm volatile("s_waitcnt lgkmcnt(0)" ::: "memory"); __builtin_amdgcn_sched_barrier(0); }
#define PRIO1 __builtin_amdgcn_s_setprio(1)
#define PRIO0 __builtin_amdgcn_s_setprio(0)

#define STAGE_A(D, KT) {                                                      \
    int sg_ = (KT) >> 3; int kof_ = ((KT) & 7) * 64;                          \
    const _Float16* ab_ = (sg_ == 1 ? klo : khi) + arow0 + kof_;              \
    gld16(ab_ + soff0,         &smem[(D) * 32768 + (w * 2 + 0) * 512]);       \
    gld16(ab_ + soff1,         &smem[(D) * 32768 + (w * 2 + 1) * 512]);       \
    gld16(ab_ + 65536 + soff0, &smem[(D) * 32768 + 8192 + (w * 2 + 0) * 512]);\
    gld16(ab_ + 65536 + soff1, &smem[(D) * 32768 + 8192 + (w * 2 + 1) * 512]);\
}
#define STAGE_B(D, KT) {                                                      \
    int sg_ = (KT) >> 3; int kof_ = ((KT) & 7) * 64;                          \
    const _Float16* bb_ = (sg_ == 2 ? qlo : qhi) + brow0 + kof_;              \
    gld16(bb_ + soff0,         &smem[(D) * 32768 + 16384 + (w * 2 + 0) * 512]);\
    gld16(bb_ + soff1,         &smem[(D) * 32768 + 16384 + (w * 2 + 1) * 512]);\
    gld16(bb_ + 65536 + soff0, &smem[(D) * 32768 + 24576 + (w * 2 + 0) * 512]);\
    gld16(bb_ + 65536 + soff1, &smem[(D) * 32768 + 24576 + (w * 2 + 1) * 512]);\
}
#define RD_A(D, HF) {                                                         \
    _Pragma("unroll") for (int ii = 0; ii < 4; ++ii)                          \
      _Pragma("unroll") for (int kk = 0; kk < 2; ++kk)                        \
        ah[ii][kk] = *(const f16x8*)&smem[(D) * 32768 + ha * 8192 +           \
                         ((HF) * 4 + ii) * 1024 + kk * 32 + rdoffh];          \
}
#define RD_B(D, HF) {                                                         \
    _Pragma("unroll") for (int jj = 0; jj < 2; ++jj)                          \
      _Pragma("unroll") for (int kk = 0; kk < 2; ++kk)                        \
        bf[(HF) * 2 + jj][kk] = *(const f16x8*)&smem[(D) * 32768 + 16384 +    \
            hb * 8192 + wb64f + ((HF) * 2 + jj) * 1024 + kk * 32 + rdoffh];   \
}
#define MM(AH, BH) {                                                          \
    _Pragma("unroll") for (int kk = 0; kk < 2; ++kk)                          \
      _Pragma("unroll") for (int ii = 0; ii < 4; ++ii)                        \
        _Pragma("unroll") for (int jj = 0; jj < 2; ++jj)                      \
          acc[(AH) * 4 + ii][(BH) * 2 + jj] =                                 \
            __builtin_amdgcn_mfma_f32_16x16x32_f16(ah[ii][kk],                \
                bf[(BH) * 2 + jj][kk], acc[(AH) * 4 + ii][(BH) * 2 + jj], 0, 0, 0); \
}
#define KTILE(D, KTN, DOSTAGE) {                                              \
    if (DOSTAGE) STAGE_A(1 - (D), KTN);                                       \
    RD_A(D, 0); RD_B(D, 0);                                                   \
    BAR; LGKM0; PRIO1; MM(0, 0); PRIO0; BAR;                                  \
    if (DOSTAGE) STAGE_B(1 - (D), KTN);                                       \
    RD_B(D, 1);                                                               \
    BAR; LGKM0; PRIO1; MM(0, 1); PRIO0; BAR;                                  \
    RD_A(D, 1);                                                               \
    BAR; LGKM0; PRIO1; MM(1, 1); PRIO0; BAR;                                  \
    PRIO1; MM(1, 0); PRIO0;                                                   \
    if (DOSTAGE) { asm volatile("s_waitcnt vmcnt(0)" ::: "memory"); }         \
    BAR;                                                                      \
}

__global__ __launch_bounds__(512, 2) void k_logits_8p(
    const _Float16* __restrict__ khi, const _Float16* __restrict__ klo,
    const _Float16* __restrict__ qhi, const _Float16* __restrict__ qlo,
    float* __restrict__ logits,       // [B][N][T]
    float* __restrict__ pval,         // [B][16][T]
    int*   __restrict__ pidx)         // [B][16][T]
{
    __shared__ __align__(16) _Float16 smem[65536];   // 128 KB, 2 x (A 32KB + B 32KB)

    // Bijective XCD-aware swizzle of the flat block id (512 = 8 XCD x 64).
    const int f  = blockIdx.x + 8 * (blockIdx.y + 16 * blockIdx.z);
    const int fs = (f & 7) * 64 + (f >> 3);
    const int t0 = (fs & 7) * 256;
    const int by = (fs >> 3) & 15;
    const int b  = fs >> 7;
    const int n0 = by * 256;

    const int tid  = threadIdx.x;
    const int w    = tid >> 6;
    const int l    = tid & 63;
    const int quad = l >> 4;
    const int l15  = l & 15;
    const int wm   = (w >> 2) * 128;   // m (n-rows) offset; A-half = w>>2
    const int ha   = w >> 2;
    const int wn   = (w & 3) * 64;     // n (t-cols) offset
    const int hb   = (w & 3) >> 1;     // B-half
    const int wb64f = (w & 1) * 4096;  // row offset within B-half (f16)

    const size_t arow0 = (size_t)n0 * CC;
    const size_t brow0 = ((size_t)b * TT + t0) * CC;

    // Pre-swizzled staging source offsets: physical chunk p -> logical s =
    // p ^ (((p>>5)&1)<<1)  (st_16x32: flip byte-bit5 on byte-bit9).
    size_t soff0, soff1;
    {
        int p0 = (w * 2 + 0) * 64 + l;
        int s0 = p0 ^ (((p0 >> 5) & 1) << 1);
        soff0 = (size_t)(s0 >> 3) * CC + (size_t)(s0 & 7) * 8;
        int p1 = (w * 2 + 1) * 64 + l;
        int s1 = p1 ^ (((p1 >> 5) & 1) << 1);
        soff1 = (size_t)(s1 >> 3) * CC + (size_t)(s1 & 7) * 8;
    }
    // Swizzled ds_read offset (f16 units) within a 128x64 half.
    const int rdoffh = (l15 * 64 + quad * 8) ^ ((((l15 >> 2) & 1)) << 4);

    f32x4 acc[8][4];
    #pragma unroll
    for (int i = 0; i < 8; ++i)
        #pragma unroll
        for (int j = 0; j < 4; ++j)
            acc[i][j] = (f32x4){0.f, 0.f, 0.f, 0.f};
    f16x8 ah[4][2];
    f16x8 bf[4][2];

    // Prologue: stage K-tile 0 into buf0.
    STAGE_A(0, 0); STAGE_B(0, 0);
    asm volatile("s_waitcnt vmcnt(0)" ::: "memory");
    BAR;

    for (int kt2 = 0; kt2 < 12; ++kt2) {
        const int kt = kt2 * 2;
        KTILE(0, kt + 1, 1);
        KTILE(1, kt + 2, kt2 < 11);
    }

    // Epilogue: store logits (i-outer, j-inner: 4x64B per row in sequence).
    {
        const size_t lb = ((size_t)b * NN + n0 + wm) * TT + t0 + wn;
        #pragma unroll
        for (int i = 0; i < 8; ++i)
            #pragma unroll
            for (int r = 0; r < 4; ++r) {
                const size_t rowoff = lb + (size_t)(i * 16 + quad * 4 + r) * TT;
                #pragma unroll
                for (int j = 0; j < 4; ++j)
                    logits[rowoff + j * 16 + l15] = acc[i][j][r] * INV_SCALE2;
            }
    }
    // Partial argmax over this block's 256 n-rows (first-max tie-break).
    float bvj[4]; int bnj[4];
    #pragma unroll
    for (int j = 0; j < 4; ++j) {
        float bv = -3.0e38f; int bn = 0;
        #pragma unroll
        for (int i = 0; i < 8; ++i)
            #pragma unroll
            for (int r = 0; r < 4; ++r) {
                float v = acc[i][j][r] * INV_SCALE2;
                int row = n0 + wm + i * 16 + quad * 4 + r;
                if (v > bv) { bv = v; bn = row; }
            }
        #pragma unroll
        for (int m = 16; m <= 32; m <<= 1) {
            float ov = __shfl_xor(bv, m, 64);
            int   on = __shfl_xor(bn, m, 64);
            if (ov > bv || (ov == bv && on < bn)) { bv = ov; bn = on; }
        }
        bvj[j] = bv; bnj[j] = bn;
    }
    // Merge wave pairs (w, w+4): lower rows (w<4) win ties via strict >.
    float* rv = (float*)smem;
    int*   ri = (int*)(smem + 1024);
    __syncthreads();
    if (w >= 4 && l < 16) {
        #pragma unroll
        for (int j = 0; j < 4; ++j) {
            rv[wn + j * 16 + l] = bvj[j];
            ri[wn + j * 16 + l] = bnj[j];
        }
    }
    __syncthreads();
    if (w < 4 && l < 16) {
        #pragma unroll
        for (int j = 0; j < 4; ++j) {
            int cl = wn + j * 16 + l;
            float bv = bvj[j]; int bn = bnj[j];
            float ov = rv[cl];
            if (ov > bv) { bv = ov; bn = ri[cl]; }
            size_t o = ((size_t)b * 16 + by) * TT + t0 + cl;
            pval[o] = bv;
            pidx[o] = bn;
        }
    }
}

// ---------------------------------------------------------------------------
// Finalize: reduce 16 partial argmaxes per (b,t), gather z_q rows from vproj.
// ---------------------------------------------------------------------------
__global__ __launch_bounds__(256) void k_finalize(
    const float* __restrict__ pval,    // [B][16][T]
    const int*   __restrict__ pidx,    // [B][16][T]
    const float* __restrict__ vproj,   // [N][C]
    float* __restrict__ idx_out,       // [B][T] (float)
    float* __restrict__ zq)            // [B][C][T]
{
    const int b  = blockIdx.y;
    const int t0 = blockIdx.x * 32;
    const int tid = threadIdx.x;

    __shared__ int sfin[32];
    if (tid < 32) {
        const int t = t0 + tid;
        float bv = -3.0e38f; int bn = 0;
        #pragma unroll
        for (int k = 0; k < 16; ++k) {
            size_t o = ((size_t)b * 16 + k) * TT + t;
            float v = pval[o];
            if (v > bv) { bv = v; bn = pidx[o]; }
        }
        idx_out[(size_t)b * TT + t] = (float)bn;
        sfin[tid] = bn;
    }
    __syncthreads();
    for (int pos = tid; pos < 32 * CC; pos += 256) {
        int c = pos >> 5, tl = pos & 31;
        zq[((size_t)b * CC + c) * TT + t0 + tl] = vproj[(size_t)sfin[tl] * CC + c];
    }
}

// ---------------------------------------------------------------------------
extern "C" void kernel_launch(void* const* d_in, const int* in_sizes, int n_in,
                              void* d_out, int out_size, void* d_ws, size_t ws_size,
                              hipStream_t stream)
{
    (void)in_sizes; (void)n_in; (void)out_size; (void)ws_size;
    const float* hs = (const float*)d_in[0];
    const float* cb = (const float*)d_in[1];
    const float* Wq = (const float*)d_in[2];
    const float* bq = (const float*)d_in[3];
    const float* Wk = (const float*)d_in[4];
    const float* bk = (const float*)d_in[5];
    const float* Wv = (const float*)d_in[6];
    const float* bv = (const float*)d_in[7];
    const float* Wp = (const float*)d_in[8];
    const float* bp = (const float*)d_in[9];

    char* ws = (char*)d_ws;
    const size_t MB = 1024 * 1024;
    _Float16* hsTh = (_Float16*)(ws);              // [B*T][C] 8 MB
    _Float16* hsTl = (_Float16*)(ws + 8  * MB);
    _Float16* qhi  = (_Float16*)(ws + 16 * MB);    // [B*T][C] 8 MB
    _Float16* qlo  = (_Float16*)(ws + 24 * MB);
    _Float16* cbhi = (_Float16*)(ws + 32 * MB);    // [N][C]   4 MB
    _Float16* cblo = (_Float16*)(ws + 36 * MB);
    _Float16* khi  = (_Float16*)(ws + 40 * MB);    // [N][C]   4 MB
    _Float16* klo  = (_Float16*)(ws + 44 * MB);
    float*    vproj= (float*)   (ws + 48 * MB);    // [N][C]   8 MB fp32
    _Float16* wqTh = (_Float16*)(ws + 56 * MB);    // [C][C]   0.5 MB each
    _Float16* wqTl = (_Float16*)(ws + 56 * MB + 524288);
    _Float16* wkTh = (_Float16*)(ws + 57 * MB);
    _Float16* wkTl = (_Float16*)(ws + 57 * MB + 524288);
    _Float16* wvTh = (_Float16*)(ws + 58 * MB);
    _Float16* wvTl = (_Float16*)(ws + 58 * MB + 524288);
    // Partial argmax buffers alias the (dead-after-proj) cbhi region.
    float* pval = (float*)(ws + 32 * MB);          // [B][16][T] 512 KB
    int*   pidx = (int*)  (ws + 33 * MB);

    float* logits = (float*)d_out;                  // B*N*T
    float* idxf   = logits + (size_t)BB * NN * TT;  // B*T
    float* zq     = idxf + (size_t)BB * TT;         // B*C*T

    // Prep
    k_split<<<dim3((NN * CC / 4 + 255) / 256), 256, 0, stream>>>(
        cb, cbhi, cblo, NN * CC / 4);
    k_tsplit<<<dim3(TT / 64, CC / 64, BB), 256, 0, stream>>>(
        hs, hsTh, hsTl, (long)CC * TT, (long)TT * CC, TT, CC);
    k_tsplit_w<<<dim3(CC / 64, CC / 64, 3), 256, 0, stream>>>(
        Wq, Wk, Wv, wqTh, wkTh, wvTh, wqTl, wkTl, wvTl);

    // All projections in one dispatch (512 blocks -> 2 blocks/CU)
    k_proj_all<<<dim3(CC / 128, 64, 2), 256, 0, stream>>>(
        hsTh, hsTl, cbhi, cblo,
        wqTh, wqTl, wkTh, wkTl, wvTh, wvTl,
        bq, bk, bv, Wp, bp,
        qhi, qlo, khi, klo, vproj);

    // Logits: 256^2-tile phase-split GEMM + fused partial argmax
    k_logits_8p<<<dim3(TT / 256, NN / 256, BB), 512, 0, stream>>>(
        khi, klo, qhi, qlo, logits, pval, pidx);

    // Final argmax reduce + gather
    k_finalize<<<dim3(TT / 32, BB), 256, 0, stream>>>(
        pval, pidx, vproj, idxf, zq);
}